// Round 1
// baseline (5224.185 us; speedup 1.0000x reference)
//
#include <hip/hip_runtime.h>
#include <cstdint>
#include <cstddef>

#define DEVINL __device__ __forceinline__

typedef __attribute__((ext_vector_type(8))) short bf16x8;
typedef __attribute__((ext_vector_type(4))) float f32x4;
typedef __attribute__((ext_vector_type(4))) unsigned short u16x4;

// ---------- constants ----------
static constexpr int B_ = 128, T_ = 256, K_ = 1024, NG = 4096;   // NG = 4*CELL gate cols
static constexpr size_t OFF_XB   = 0;                              // x bf16 [32768][1024]
static constexpr size_t OFF_WHT  = OFF_XB  + (size_t)32768*1024*2; // Wh^T bf16 [4096][1024]
static constexpr size_t OFF_WXT  = OFF_WHT + (size_t)4096*1024*2;  // Wx^T bf16 [4096][1024]
static constexpr size_t OFF_WCT  = OFF_WXT + (size_t)4096*1024*2;  // Wc^T bf16 [1024][1024]
static constexpr size_t OFF_BIAS = OFF_WCT + (size_t)1024*1024*2;  // bias_all f32 [4096]
static constexpr size_t OFF_XW   = OFF_BIAS + 4096*4;              // XW bf16 [32768][4096]
static constexpr size_t OFF_H    = OFF_XW  + (size_t)32768*4096*2; // h bf16 [32768][1024]
static constexpr size_t OFF_CF   = OFF_H   + (size_t)32768*1024*2; // cell f32 x2 [128][1024]
static constexpr size_t OFF_CB   = OFF_CF  + (size_t)2*128*1024*4; // cell bf16 x2
static constexpr size_t WS_NEEDED = OFF_CB + (size_t)2*128*1024*2;

// ---------- helpers ----------
DEVINL unsigned short f2b(float f) {
  union { float f; unsigned u; } v; v.f = f;
  unsigned r = (v.u + 0x7FFFu + ((v.u >> 16) & 1u)) >> 16;  // RNE
  return (unsigned short)r;
}
DEVINL float b2f(unsigned short h) {
  union { unsigned u; float f; } v; v.u = ((unsigned)h) << 16;
  return v.f;
}
DEVINL float sigmoidf_(float x) { return 1.0f / (1.0f + __expf(-x)); }

DEVINL void gload16(const void* g, void* l) {
  __builtin_amdgcn_global_load_lds(
      (const __attribute__((address_space(1))) void*)g,
      (__attribute__((address_space(3))) void*)l, 16, 0, 0);
}

// ---------- conversions ----------
__global__ void cvt_x_kernel(const float* __restrict__ x, unsigned short* __restrict__ xb) {
  size_t i = ((size_t)blockIdx.x * 256 + threadIdx.x) * 4;
  float4 v = *(const float4*)(x + i);
  u16x4 o; o.x = f2b(v.x); o.y = f2b(v.y); o.z = f2b(v.z); o.w = f2b(v.w);
  *(u16x4*)(xb + i) = o;
}

// Wh^T[4j+g][k] = Wg[k][j]; Wx^T[4j+g][k] = Wg[1024+k][j]; bias_all[4j+g] = b_g[j]
__global__ void cvt_w_kernel(const float* __restrict__ Wf, const float* __restrict__ Wi1,
                             const float* __restrict__ Wi2, const float* __restrict__ Wo,
                             const float* __restrict__ bf_, const float* __restrict__ bi1,
                             const float* __restrict__ bi2, const float* __restrict__ bo,
                             unsigned short* __restrict__ WhT, unsigned short* __restrict__ WxT,
                             float* __restrict__ biasAll) {
  int idx = blockIdx.x * 256 + threadIdx.x;   // 4096*1024 total
  int k = idx & 1023, gc = idx >> 10;
  int j = gc >> 2, g = gc & 3;
  const float* W = (g == 0) ? Wf : (g == 1) ? Wi1 : (g == 2) ? Wi2 : Wo;
  WhT[idx] = f2b(W[(size_t)k * 1024 + j]);
  WxT[idx] = f2b(W[(size_t)(k + 1024) * 1024 + j]);
  if (k == 0) {
    const float* bb = (g == 0) ? bf_ : (g == 1) ? bi1 : (g == 2) ? bi2 : bo;
    biasAll[gc] = bb[j];
  }
}

__global__ void cvt_wc_kernel(const float* __restrict__ Wc, unsigned short* __restrict__ WcT) {
  int idx = blockIdx.x * 256 + threadIdx.x;   // 1024*1024 total
  int k = idx & 1023, n = idx >> 10;
  WcT[idx] = f2b(Wc[(size_t)k * 1024 + n]);
}

// ---------- 128x128 bf16 GEMM, B given as B^T [N][K], C = A@B + bias ----------
template<bool OUT_F32>
__global__ __launch_bounds__(256)
void gemm_bt(const unsigned short* __restrict__ A,   // [M][K] bf16
             const unsigned short* __restrict__ Bt,  // [N][K] bf16
             const float* __restrict__ bias,         // [N] f32
             void* __restrict__ C,
             int M, int N, int K) {
  __shared__ unsigned short sA[128 * 64];
  __shared__ unsigned short sB[128 * 64];
  const int tid  = threadIdx.x;
  const int lane = tid & 63;
  const int wid  = tid >> 6;
  const int m0   = blockIdx.y * 128;
  const int n0   = blockIdx.x * 128;
  const int wm   = (wid >> 1) * 64;
  const int wn   = (wid & 1) * 64;

  f32x4 acc[4][4];
#pragma unroll
  for (int i = 0; i < 4; ++i)
#pragma unroll
    for (int j = 0; j < 4; ++j) acc[i][j] = (f32x4){0.f, 0.f, 0.f, 0.f};

  for (int k0 = 0; k0 < K; k0 += 64) {
#pragma unroll
    for (int p = 0; p < 4; ++p) {
      int t = p * 256 + tid;
      int r = t >> 3, c = t & 7;                    // row 0..127, 16B chunk 0..7
      gload16(A  + (size_t)(m0 + r) * K + k0 + c * 8, (char*)sA + p * 4096 + wid * 1024);
      gload16(Bt + (size_t)(n0 + r) * K + k0 + c * 8, (char*)sB + p * 4096 + wid * 1024);
    }
    __syncthreads();
#pragma unroll
    for (int kk = 0; kk < 2; ++kk) {
      bf16x8 av[4], bv[4];
#pragma unroll
      for (int mi = 0; mi < 4; ++mi)
        av[mi] = *(const bf16x8*)&sA[(wm + mi * 16 + (lane & 15)) * 64 + kk * 32 + (lane >> 4) * 8];
#pragma unroll
      for (int ni = 0; ni < 4; ++ni)
        bv[ni] = *(const bf16x8*)&sB[(wn + ni * 16 + (lane & 15)) * 64 + kk * 32 + (lane >> 4) * 8];
#pragma unroll
      for (int mi = 0; mi < 4; ++mi)
#pragma unroll
        for (int ni = 0; ni < 4; ++ni)
          acc[mi][ni] = __builtin_amdgcn_mfma_f32_16x16x32_bf16(av[mi], bv[ni], acc[mi][ni], 0, 0, 0);
    }
    __syncthreads();
  }

#pragma unroll
  for (int mi = 0; mi < 4; ++mi)
#pragma unroll
    for (int ni = 0; ni < 4; ++ni)
#pragma unroll
      for (int r = 0; r < 4; ++r) {
        int row = m0 + wm + mi * 16 + (lane >> 4) * 4 + r;
        int col = n0 + wn + ni * 16 + (lane & 15);
        float v = acc[mi][ni][r] + bias[col];
        if (OUT_F32) ((float*)C)[(size_t)row * N + col] = v;
        else ((unsigned short*)C)[(size_t)row * N + col] = f2b(v);
      }
}

// ---------- per-step: gates = cell @ Wh^T + XW[t], fused elementwise ----------
__global__ __launch_bounds__(256)
void lstm_step(const unsigned short* __restrict__ cinB,  // [128][1024] bf16 (c_t)
               const float* __restrict__ cinF,           // [128][1024] f32  (c_t)
               unsigned short* __restrict__ coutB,       // c_{t+1} bf16
               float* __restrict__ coutF,                // c_{t+1} f32
               const unsigned short* __restrict__ WhT,   // [4096][1024]
               const unsigned short* __restrict__ XW,    // [32768][4096], row = b*256+t
               unsigned short* __restrict__ H,           // [32768][1024], row = b*256+t
               int t) {
  __shared__ char smem[4096 + 16384];                    // sA 4KB | sB 16KB; reused as sP
  unsigned short* sA = (unsigned short*)smem;
  unsigned short* sB = (unsigned short*)(smem + 4096);
  float* sP = (float*)smem;                              // [32][132] = 16896B

  const int tid  = threadIdx.x;
  const int lane = tid & 63;
  const int wid  = tid >> 6;
  const int m0   = blockIdx.y * 32;    // batch rows
  const int n0   = blockIdx.x * 128;   // gate cols
  const int wm   = (wid >> 1) * 16;
  const int wn   = (wid & 1) * 64;

  f32x4 acc[4];
#pragma unroll
  for (int ni = 0; ni < 4; ++ni) acc[ni] = (f32x4){0.f, 0.f, 0.f, 0.f};

  for (int k0 = 0; k0 < 1024; k0 += 64) {
    {  // A tile [32][64]: one pass
      int r = tid >> 3, c = tid & 7;
      gload16(cinB + (size_t)(m0 + r) * 1024 + k0 + c * 8, (char*)sA + wid * 1024);
    }
#pragma unroll
    for (int p = 0; p < 4; ++p) {      // B tile [128][64]: four passes
      int tt = p * 256 + tid;
      int r = tt >> 3, c = tt & 7;
      gload16(WhT + (size_t)(n0 + r) * 1024 + k0 + c * 8, (char*)sB + p * 4096 + wid * 1024);
    }
    __syncthreads();
#pragma unroll
    for (int kk = 0; kk < 2; ++kk) {
      bf16x8 a = *(const bf16x8*)&sA[(wm + (lane & 15)) * 64 + kk * 32 + (lane >> 4) * 8];
#pragma unroll
      for (int ni = 0; ni < 4; ++ni) {
        bf16x8 b = *(const bf16x8*)&sB[(wn + ni * 16 + (lane & 15)) * 64 + kk * 32 + (lane >> 4) * 8];
        acc[ni] = __builtin_amdgcn_mfma_f32_16x16x32_bf16(a, b, acc[ni], 0, 0, 0);
      }
    }
    __syncthreads();
  }

  // redistribute preacts via LDS (padded stride 132 to dodge bank conflicts)
#pragma unroll
  for (int ni = 0; ni < 4; ++ni)
#pragma unroll
    for (int r = 0; r < 4; ++r)
      sP[(wm + (lane >> 4) * 4 + r) * 132 + wn + ni * 16 + (lane & 15)] = acc[ni][r];
  __syncthreads();

  // elementwise: 32 rows x 32 cell-cols, 4 items/thread
#pragma unroll
  for (int q = 0; q < 4; ++q) {
    int i  = q * 256 + tid;
    int bl = i >> 5, jl = i & 31;
    int b  = m0 + bl;
    int j  = (n0 >> 2) + jl;
    size_t xwr = ((size_t)b * 256 + t) * 4096 + n0 + jl * 4;
    u16x4 xw = *(const u16x4*)(XW + xwr);
    f32x4 p  = *(const f32x4*)&sP[bl * 132 + jl * 4];
    float pf = p.x + b2f(xw.x);
    float pi = p.y + b2f(xw.y);
    float pg = p.z + b2f(xw.z);
    float po = p.w + b2f(xw.w);
    float f  = sigmoidf_(pf);
    float i1 = sigmoidf_(pi);
    float i2 = tanhf(pg);
    float o  = sigmoidf_(po);
    float c2 = cinF[b * 1024 + j] * f + i1 * i2;
    coutF[b * 1024 + j] = c2;
    coutB[b * 1024 + j] = f2b(c2);
    H[((size_t)b * 256 + t) * 1024 + j] = f2b(o * tanhf(c2));
  }
}

// ---------- launcher ----------
extern "C" void kernel_launch(void* const* d_in, const int* in_sizes, int n_in,
                              void* d_out, int out_size, void* d_ws, size_t ws_size,
                              hipStream_t stream) {
  const float* x   = (const float*)d_in[0];
  const float* Wf  = (const float*)d_in[1];
  const float* bfv = (const float*)d_in[2];
  const float* Wi1 = (const float*)d_in[3];
  const float* bi1 = (const float*)d_in[4];
  const float* Wi2 = (const float*)d_in[5];
  const float* bi2 = (const float*)d_in[6];
  const float* Wo  = (const float*)d_in[7];
  const float* bo  = (const float*)d_in[8];
  const float* Wc  = (const float*)d_in[9];
  const float* bc  = (const float*)d_in[10];
  float* out = (float*)d_out;

  if (ws_size < WS_NEEDED) return;  // visible failure instead of memory corruption

  char* ws = (char*)d_ws;
  unsigned short* xb      = (unsigned short*)(ws + OFF_XB);
  unsigned short* WhT     = (unsigned short*)(ws + OFF_WHT);
  unsigned short* WxT     = (unsigned short*)(ws + OFF_WXT);
  unsigned short* WcT     = (unsigned short*)(ws + OFF_WCT);
  float*          biasAll = (float*)(ws + OFF_BIAS);
  unsigned short* XW      = (unsigned short*)(ws + OFF_XW);
  unsigned short* H       = (unsigned short*)(ws + OFF_H);
  float*          cF0     = (float*)(ws + OFF_CF);
  float*          cF1     = (float*)(ws + OFF_CF + (size_t)128 * 1024 * 4);
  unsigned short* cB0     = (unsigned short*)(ws + OFF_CB);
  unsigned short* cB1     = (unsigned short*)(ws + OFF_CB + (size_t)128 * 1024 * 2);

  float*          cF[2] = {cF0, cF1};
  unsigned short* cB[2] = {cB0, cB1};

  hipMemsetAsync(cF0, 0, (size_t)128 * 1024 * 4, stream);
  hipMemsetAsync(cB0, 0, (size_t)128 * 1024 * 2, stream);

  cvt_x_kernel <<<32768, 256, 0, stream>>>(x, xb);
  cvt_w_kernel <<<16384, 256, 0, stream>>>(Wf, Wi1, Wi2, Wo, bfv, bi1, bi2, bo, WhT, WxT, biasAll);
  cvt_wc_kernel<<< 4096, 256, 0, stream>>>(Wc, WcT);

  // XW = x @ Wx_all + biases   (M=32768, N=4096, K=1024), bf16 out
  gemm_bt<false><<<dim3(32, 256), 256, 0, stream>>>(xb, WxT, biasAll, XW, 32768, 4096, 1024);

  // sequential recurrence
  for (int t = 0; t < 256; ++t) {
    lstm_step<<<dim3(32, 4), 256, 0, stream>>>(cB[t & 1], cF[t & 1],
                                               cB[(t + 1) & 1], cF[(t + 1) & 1],
                                               WhT, XW, H, t);
  }

  // output_sequence = h @ Wc + bc  (M=32768, N=1024, K=1024), f32 out
  gemm_bt<true><<<dim3(8, 256), 256, 0, stream>>>(H, WcT, bc, out, 32768, 1024, 1024);

  // final cell state (t=255 writes buffer 0)
  hipMemcpyAsync(out + (size_t)32768 * 1024, cF0, (size_t)128 * 1024 * 4,
                 hipMemcpyDeviceToDevice, stream);
}